// Round 5
// baseline (466.971 us; speedup 1.0000x reference)
//
#include <hip/hip_runtime.h>

#define TSEQ 2048
#define BB 4
#define CDIM 1024
#define NH 16
#define HD 64
#define MR (TSEQ*BB)   // 8192 rows
#define C2SCALE 0.045084220f   // log2(e)/sqrt(CDIM) = log2(e)/32

typedef __attribute__((ext_vector_type(8))) short sh8;   // 8 bf16 = 4 VGPRs
typedef __attribute__((ext_vector_type(4))) short sh4;   // 4 bf16
typedef __attribute__((ext_vector_type(4))) float f4;    // MFMA C/D

__device__ __forceinline__ unsigned short f2bf(float x){
  unsigned u = __builtin_bit_cast(unsigned, x);
  u += 0x7fffu + ((u>>16)&1u);          // round-to-nearest-even
  return (unsigned short)(u>>16);
}

// pack two floats -> two bf16 (round-half-up) in one dword: [hi16(a) : hi16(b)]
__device__ __forceinline__ unsigned pk2(float a, float b){
  unsigned ua = __builtin_bit_cast(unsigned, a) + 0x8000u;
  unsigned ub = __builtin_bit_cast(unsigned, b) + 0x8000u;
  return __builtin_amdgcn_perm(ua, ub, 0x07060302u);  // bytes a[3],a[2],b[3],b[2]
}

__device__ __forceinline__ void gll16(const unsigned short* g, unsigned short* l){
  __builtin_amdgcn_global_load_lds(
      (const __attribute__((address_space(1))) unsigned int*)g,
      (__attribute__((address_space(3))) unsigned int*)l, 16, 0, 0);
}

// ---------------- fp32 -> bf16 conversion, fused ----------------
__global__ void conv_x(const float* __restrict__ a, const float* __restrict__ b,
                       unsigned short* __restrict__ ya, unsigned short* __restrict__ yb){
  const float* s = blockIdx.y ? b : a;
  unsigned short* d = blockIdx.y ? yb : ya;
  int i = (blockIdx.x*256 + threadIdx.x)*4;
  f4 v = *(const f4*)(s+i);
  sh4 o;
  o.x = (short)f2bf(v.x); o.y = (short)f2bf(v.y);
  o.z = (short)f2bf(v.z); o.w = (short)f2bf(v.w);
  *(sh4*)(d+i) = o;
}

__global__ void conv_w(const float* __restrict__ w0, const float* __restrict__ w1,
                       const float* __restrict__ w2, const float* __restrict__ w3,
                       unsigned short* __restrict__ y0, unsigned short* __restrict__ y1,
                       unsigned short* __restrict__ y2, unsigned short* __restrict__ y3){
  const float* s; unsigned short* d;
  switch(blockIdx.y){
    case 0: s=w0; d=y0; break;
    case 1: s=w1; d=y1; break;
    case 2: s=w2; d=y2; break;
    default: s=w3; d=y3; break;
  }
  int i = (blockIdx.x*256 + threadIdx.x)*4;
  f4 v = *(const f4*)(s+i);
  sh4 o;
  o.x = (short)f2bf(v.x); o.y = (short)f2bf(v.y);
  o.z = (short)f2bf(v.z); o.w = (short)f2bf(v.w);
  *(sh4*)(d+i) = o;
}

// ---------------- GEMM: C[m][n] = sum_k A[m][k]*W[n][k] + bias[n] ----------------
// MODE 2: fp32 row-major. MODE 3: bf16 row-major scaled by C2SCALE (Q path).
template<int MODE>
__global__ __launch_bounds__(256,2) void gemm_bt(
    const unsigned short* __restrict__ A, const unsigned short* __restrict__ Bw,
    const float* __restrict__ bias, void* __restrict__ Cout){
  __shared__ unsigned short As[128*32];
  __shared__ unsigned short Bs[128*32];
  const int tid  = threadIdx.x;
  const int wave = tid>>6, lane = tid&63;
  const int g = lane>>4, c = lane&15;
  const int m0 = blockIdx.x*128, n0 = blockIdx.y*128;
  const int wr = wave>>1, wc = wave&1;
  f4 acc[4][4] = {};
  const int r0 = tid>>2, cc0 = tid&3;
  const unsigned short* Ag = A  + (size_t)(m0+r0)*CDIM + cc0*8;
  const unsigned short* Bg = Bw + (size_t)(n0+r0)*CDIM + cc0*8;

  for (int k0=0; k0<CDIM; k0+=32){
    __syncthreads();
    gll16(Ag + k0,                    As + tid*8);
    gll16(Ag + (size_t)64*CDIM + k0,  As + (256+tid)*8);
    gll16(Bg + k0,                    Bs + tid*8);
    gll16(Bg + (size_t)64*CDIM + k0,  Bs + (256+tid)*8);
    __syncthreads();
    sh8 af[4], bfr[4];
#pragma unroll
    for (int mt=0; mt<4; mt++) af[mt]  = *(const sh8*)(As + (wr*64+mt*16+c)*32 + g*8);
#pragma unroll
    for (int nt=0; nt<4; nt++) bfr[nt] = *(const sh8*)(Bs + (wc*64+nt*16+c)*32 + g*8);
#pragma unroll
    for (int mt=0; mt<4; mt++)
#pragma unroll
      for (int nt=0; nt<4; nt++)
        acc[mt][nt] = __builtin_amdgcn_mfma_f32_16x16x32_bf16(af[mt], bfr[nt], acc[mt][nt], 0,0,0);
  }

#pragma unroll
  for (int nt=0; nt<4; nt++){
    int nn = n0 + wc*64 + nt*16 + c;
    float bsv = bias[nn];
#pragma unroll
    for (int mt=0; mt<4; mt++){
      int mb = m0 + wr*64 + mt*16 + 4*g;
#pragma unroll
      for (int r=0; r<4; r++){
        float v = acc[mt][nt][r] + bsv;
        int mm = mb + r;
        if (MODE==3){
          ((unsigned short*)Cout)[(size_t)mm*CDIM + nn] = f2bf(v*C2SCALE);
        } else {
          ((float*)Cout)[(size_t)mm*CDIM + nn] = v;
        }
      }
    }
  }
}

// ---------------- fused K+V GEMM: one A-tile, two B-tiles, two outputs ----------------
__global__ __launch_bounds__(256,2) void gemm_kv(
    const unsigned short* __restrict__ A,
    const unsigned short* __restrict__ Bk, const unsigned short* __restrict__ Bv,
    const float* __restrict__ biask, const float* __restrict__ biasv,
    unsigned short* __restrict__ Kout, unsigned short* __restrict__ Vout){
  __shared__ unsigned short As[128*32];
  __shared__ unsigned short Bs1[128*32];
  __shared__ unsigned short Bs2[128*32];
  const int tid  = threadIdx.x;
  const int wave = tid>>6, lane = tid&63;
  const int g = lane>>4, c = lane&15;
  const int m0 = blockIdx.x*128, n0 = blockIdx.y*128;
  const int wr = wave>>1, wc = wave&1;
  f4 acck[4][4] = {}, accv[4][4] = {};
  const int r0 = tid>>2, cc0 = tid&3;
  const unsigned short* Ag  = A  + (size_t)(m0+r0)*CDIM + cc0*8;
  const unsigned short* Bkg = Bk + (size_t)(n0+r0)*CDIM + cc0*8;
  const unsigned short* Bvg = Bv + (size_t)(n0+r0)*CDIM + cc0*8;

  for (int k0=0; k0<CDIM; k0+=32){
    __syncthreads();
    gll16(Ag  + k0,                    As  + tid*8);
    gll16(Ag  + (size_t)64*CDIM + k0,  As  + (256+tid)*8);
    gll16(Bkg + k0,                    Bs1 + tid*8);
    gll16(Bkg + (size_t)64*CDIM + k0,  Bs1 + (256+tid)*8);
    gll16(Bvg + k0,                    Bs2 + tid*8);
    gll16(Bvg + (size_t)64*CDIM + k0,  Bs2 + (256+tid)*8);
    __syncthreads();
    sh8 af[4], bk4[4], bv4[4];
#pragma unroll
    for (int mt=0; mt<4; mt++) af[mt]  = *(const sh8*)(As  + (wr*64+mt*16+c)*32 + g*8);
#pragma unroll
    for (int nt=0; nt<4; nt++) bk4[nt] = *(const sh8*)(Bs1 + (wc*64+nt*16+c)*32 + g*8);
#pragma unroll
    for (int nt=0; nt<4; nt++) bv4[nt] = *(const sh8*)(Bs2 + (wc*64+nt*16+c)*32 + g*8);
#pragma unroll
    for (int mt=0; mt<4; mt++)
#pragma unroll
      for (int nt=0; nt<4; nt++){
        acck[mt][nt] = __builtin_amdgcn_mfma_f32_16x16x32_bf16(af[mt], bk4[nt], acck[mt][nt], 0,0,0);
        accv[mt][nt] = __builtin_amdgcn_mfma_f32_16x16x32_bf16(af[mt], bv4[nt], accv[mt][nt], 0,0,0);
      }
  }

#pragma unroll
  for (int nt=0; nt<4; nt++){
    int nn = n0 + wc*64 + nt*16 + c;
    float bkv = biask[nn], bvv = biasv[nn];
#pragma unroll
    for (int mt=0; mt<4; mt++){
      int mb = m0 + wr*64 + mt*16 + 4*g;
#pragma unroll
      for (int r=0; r<4; r++){
        int mm = mb + r;
        Kout[(size_t)mm*CDIM + nn] = f2bf(acck[mt][nt][r] + bkv);
        int t = mm>>2, bb = mm&3, h = nn>>6, d = nn&63;
        Vout[(((size_t)bb*NH + h)*HD + d)*TSEQ + t] = f2bf(accv[mt][nt][r] + bvv);
      }
    }
  }
}

// ---------------- flash attention, S^T / O^T, 2 q-tiles per block ----------------
// Round-5 change vs round 4: softmax processed IMMEDIATELY per kf (16-key band)
// so live S-state is 16 VGPRs (was 64) -> no scratch spills (round-4 failure:
// WRITE_SIZE 409MB of spill traffic at VGPR_Count=128). af/vf reuse across both
// q-tiles and XCD swizzle retained. oacc stays in AGPRs.
__global__ __launch_bounds__(256,2) void attn_kernel(
    const unsigned short* __restrict__ Q, const unsigned short* __restrict__ Kb,
    const unsigned short* __restrict__ Vt, unsigned short* __restrict__ O){
  __shared__ unsigned short Ks[128*64];        // (key, d), chunk ^= row&7
  __shared__ unsigned short Vs[64*128];        // (d, key), chunk ^= d&15
  __shared__ unsigned short Ps[4][2][32*64];   // per-wave, per-qtile (q, key-half)
  const int tid=threadIdx.x, wave=tid>>6, lane=tid&63;
  const int g=lane>>4, c=lane&15;
  const int gx = blockIdx.x;                   // 512 linear blocks
  const int bh = ((gx>>6)<<3) | (gx&7);        // all qts of a bh share gx%8 (same XCD)
  const int qt = (gx>>3)&7;
  const int b = bh>>4, h = bh&15;

  // persistent Q B-fragments for both q-tiles
  sh8 qfr[2][2][2];                            // [qtile][qf][kc]
#pragma unroll
  for (int qtile=0; qtile<2; qtile++)
#pragma unroll
    for (int qf=0; qf<2; qf++)
#pragma unroll
      for (int kc=0; kc<2; kc++){
        int t = qt*256 + qtile*128 + wave*32 + qf*16 + c;
        qfr[qtile][qf][kc] = *(const sh8*)(Q + ((size_t)t*BB + b)*CDIM + h*HD + kc*32 + g*8);
      }

  f4 oacc[2][4][2] = {};                       // [qtile][d-frag][q-frag]  (AGPRs)
  float lrun[2][2] = {};

  for (int k0=0; k0<TSEQ; k0+=128){
    __syncthreads();
#pragma unroll
    for (int i=0; i<4; i++){                   // stage K tile (128 keys x 64 d), swizzled
      int cc = i*256+tid, row = cc>>3, ch = (cc&7) ^ (row&7);
      gll16(Kb + ((size_t)(k0+row)*BB + b)*CDIM + h*HD + ch*8, Ks + cc*8);
    }
#pragma unroll
    for (int i=0; i<4; i++){                   // stage V^T tile (64 d x 128 keys), swizzled
      int cc = i*256+tid, d = cc>>4, ch = (cc&15) ^ (d&15);
      gll16(Vt + ((size_t)(b*NH+h)*HD + d)*TSEQ + k0 + ch*8, Vs + cc*8);
    }
    __syncthreads();

#pragma unroll
    for (int half=0; half<2; half++){
      // per 16-key band: S MFMAs then IMMEDIATE exp2+pack (keeps live S small)
#pragma unroll
      for (int kfl=0; kfl<4; kfl++){
        int kf = half*4 + kfl;
        sh8 af[2];
#pragma unroll
        for (int kc=0; kc<2; kc++){
          int ch = (kc*4+g) ^ (c&7);
          af[kc] = *(const sh8*)(Ks + (kf*16+c)*64 + ch*8);
        }
        f4 s[2][2] = {};                       // [qtile][qf] — 16 VGPRs live
#pragma unroll
        for (int qtile=0; qtile<2; qtile++)
#pragma unroll
          for (int kc=0; kc<2; kc++)
#pragma unroll
            for (int qf=0; qf<2; qf++)
              s[qtile][qf] = __builtin_amdgcn_mfma_f32_16x16x32_bf16(
                  af[kc], qfr[qtile][qf][kc], s[qtile][qf],0,0,0);
#pragma unroll
        for (int qtile=0; qtile<2; qtile++)
#pragma unroll
          for (int qf=0; qf<2; qf++){
            float p0 = __builtin_amdgcn_exp2f(s[qtile][qf][0]);
            float p1 = __builtin_amdgcn_exp2f(s[qtile][qf][1]);
            float p2 = __builtin_amdgcn_exp2f(s[qtile][qf][2]);
            float p3 = __builtin_amdgcn_exp2f(s[qtile][qf][3]);
            lrun[qtile][qf] += (p0+p1)+(p2+p3);
            uint2 pr; pr.x = pk2(p1, p0); pr.y = pk2(p3, p2);
            int js = (kfl*4+g) ^ (c&14);
            *(uint2*)(Ps[wave][qtile] + (qf*16+c)*64 + js*4) = pr;
          }
      }

      // PV: vf shared across q-tiles and q-frags (4 MFMA per Vs read)
#pragma unroll
      for (int kc2l=0; kc2l<2; kc2l++){
        int kc2 = half*2 + kc2l;
        sh8 pf[2][2];
#pragma unroll
        for (int qtile=0; qtile<2; qtile++)
#pragma unroll
          for (int qf=0; qf<2; qf++){
            int j0 = kc2l*8 + 2*g;
            pf[qtile][qf] = *(const sh8*)(Ps[wave][qtile] + (qf*16+c)*64 + (j0^(c&14))*4);
          }
#pragma unroll
        for (int df=0; df<4; df++){
          int ch = (kc2*4+g) ^ c;
          sh8 vf = *(const sh8*)(Vs + (df*16+c)*128 + ch*8);
#pragma unroll
          for (int qtile=0; qtile<2; qtile++)
#pragma unroll
            for (int qf=0; qf<2; qf++)
              oacc[qtile][df][qf] = __builtin_amdgcn_mfma_f32_16x16x32_bf16(
                  vf, pf[qtile][qf], oacc[qtile][df][qf],0,0,0);
        }
      }
    }
  }

  // epilogue: normalize + store O[(b*TSEQ+t), h*HD+d]
#pragma unroll
  for (int qtile=0; qtile<2; qtile++)
#pragma unroll
    for (int qf=0; qf<2; qf++){
      float l = lrun[qtile][qf];
      l += __shfl_xor(l, 16, 64);
      l += __shfl_xor(l, 32, 64);
      float inv = 1.0f/l;
      int t = qt*256 + qtile*128 + wave*32 + qf*16 + c;
#pragma unroll
      for (int df=0; df<4; df++){
        uint2 pr;
        pr.x = pk2(oacc[qtile][df][qf][1]*inv, oacc[qtile][df][qf][0]*inv);
        pr.y = pk2(oacc[qtile][df][qf][3]*inv, oacc[qtile][df][qf][2]*inv);
        *(uint2*)(O + ((size_t)b*TSEQ + t)*CDIM + h*HD + df*16 + 4*g) = pr;
      }
    }
}

extern "C" void kernel_launch(void* const* d_in, const int* in_sizes, int n_in,
                              void* d_out, int out_size, void* d_ws, size_t ws_size,
                              hipStream_t stream){
  (void)in_sizes; (void)n_in; (void)out_size; (void)ws_size;
  const float* x1 = (const float*)d_in[0];
  const float* x2 = (const float*)d_in[1];
  const float* Wq = (const float*)d_in[2];
  const float* bq = (const float*)d_in[3];
  const float* Wk = (const float*)d_in[4];
  const float* bk = (const float*)d_in[5];
  const float* Wv = (const float*)d_in[6];
  const float* bv = (const float*)d_in[7];
  const float* Wu = (const float*)d_in[8];
  const float* bu = (const float*)d_in[9];

  unsigned short* ws = (unsigned short*)d_ws;
  size_t o = 0;
  unsigned short* x1b = ws + o; o += (size_t)MR*CDIM;
  unsigned short* x2b = ws + o; o += (size_t)MR*CDIM;
  unsigned short* wqb = ws + o; o += (size_t)CDIM*CDIM;
  unsigned short* wkb = ws + o; o += (size_t)CDIM*CDIM;
  unsigned short* wvb = ws + o; o += (size_t)CDIM*CDIM;
  unsigned short* wub = ws + o; o += (size_t)CDIM*CDIM;
  unsigned short* Qb  = ws + o; o += (size_t)MR*CDIM;
  unsigned short* Kbf = ws + o; o += (size_t)MR*CDIM;
  unsigned short* Vtb = ws + o; o += (size_t)MR*CDIM;
  unsigned short* Ob  = x1b;   // x1b dead after Q GEMM; reuse for attention output

  conv_x<<<dim3((MR*CDIM)/1024, 2),   256, 0, stream>>>(x1, x2, x1b, x2b);
  conv_w<<<dim3((CDIM*CDIM)/1024, 4), 256, 0, stream>>>(Wq, Wk, Wv, Wu, wqb, wkb, wvb, wub);

  dim3 gg(MR/128, CDIM/128);
  gemm_bt<3><<<gg, 256, 0, stream>>>(x1b, wqb, bq, Qb);           // Q, pre-scaled
  gemm_kv  <<<gg, 256, 0, stream>>>(x2b, wkb, wvb, bk, bv, Kbf, Vtb);
  attn_kernel<<<dim3(512), 256, 0, stream>>>(Qb, Kbf, Vtb, Ob);
  gemm_bt<2><<<gg, 256, 0, stream>>>(Ob, wub, bu, (float*)d_out);
}

// Round 6
// 374.261 us; speedup vs baseline: 1.2477x; 1.2477x over previous
//
#include <hip/hip_runtime.h>

#define TSEQ 2048
#define BB 4
#define CDIM 1024
#define NH 16
#define HD 64
#define MR (TSEQ*BB)   // 8192 rows
#define C2SCALE 0.045084220f   // log2(e)/sqrt(CDIM) = log2(e)/32

typedef __attribute__((ext_vector_type(8))) short sh8;   // 8 bf16 = 4 VGPRs
typedef __attribute__((ext_vector_type(4))) short sh4;   // 4 bf16
typedef __attribute__((ext_vector_type(4))) float f4;    // MFMA C/D

__device__ __forceinline__ unsigned short f2bf(float x){
  unsigned u = __builtin_bit_cast(unsigned, x);
  u += 0x7fffu + ((u>>16)&1u);          // round-to-nearest-even
  return (unsigned short)(u>>16);
}

// pack two floats -> two bf16 (round-half-up) in one dword: [hi16(a) : hi16(b)]
__device__ __forceinline__ unsigned pk2(float a, float b){
  unsigned ua = __builtin_bit_cast(unsigned, a) + 0x8000u;
  unsigned ub = __builtin_bit_cast(unsigned, b) + 0x8000u;
  return __builtin_amdgcn_perm(ua, ub, 0x07060302u);  // bytes a[3],a[2],b[3],b[2]
}

__device__ __forceinline__ void gll16(const unsigned short* g, unsigned short* l){
  __builtin_amdgcn_global_load_lds(
      (const __attribute__((address_space(1))) unsigned int*)g,
      (__attribute__((address_space(3))) unsigned int*)l, 16, 0, 0);
}

// ---------------- fp32 -> bf16 conversion, fused ----------------
__global__ void conv_x(const float* __restrict__ a, const float* __restrict__ b,
                       unsigned short* __restrict__ ya, unsigned short* __restrict__ yb){
  const float* s = blockIdx.y ? b : a;
  unsigned short* d = blockIdx.y ? yb : ya;
  int i = (blockIdx.x*256 + threadIdx.x)*4;
  f4 v = *(const f4*)(s+i);
  sh4 o;
  o.x = (short)f2bf(v.x); o.y = (short)f2bf(v.y);
  o.z = (short)f2bf(v.z); o.w = (short)f2bf(v.w);
  *(sh4*)(d+i) = o;
}

__global__ void conv_w(const float* __restrict__ w0, const float* __restrict__ w1,
                       const float* __restrict__ w2, const float* __restrict__ w3,
                       unsigned short* __restrict__ y0, unsigned short* __restrict__ y1,
                       unsigned short* __restrict__ y2, unsigned short* __restrict__ y3){
  const float* s; unsigned short* d;
  switch(blockIdx.y){
    case 0: s=w0; d=y0; break;
    case 1: s=w1; d=y1; break;
    case 2: s=w2; d=y2; break;
    default: s=w3; d=y3; break;
  }
  int i = (blockIdx.x*256 + threadIdx.x)*4;
  f4 v = *(const f4*)(s+i);
  sh4 o;
  o.x = (short)f2bf(v.x); o.y = (short)f2bf(v.y);
  o.z = (short)f2bf(v.z); o.w = (short)f2bf(v.w);
  *(sh4*)(d+i) = o;
}

// ---------------- GEMM: C[m][n] = sum_k A[m][k]*W[n][k] + bias[n] ----------------
// MODE 2: fp32 row-major. MODE 3: bf16 row-major scaled by C2SCALE (Q path).
template<int MODE>
__global__ __launch_bounds__(256,2) void gemm_bt(
    const unsigned short* __restrict__ A, const unsigned short* __restrict__ Bw,
    const float* __restrict__ bias, void* __restrict__ Cout){
  __shared__ unsigned short As[128*32];
  __shared__ unsigned short Bs[128*32];
  const int tid  = threadIdx.x;
  const int wave = tid>>6, lane = tid&63;
  const int g = lane>>4, c = lane&15;
  const int m0 = blockIdx.x*128, n0 = blockIdx.y*128;
  const int wr = wave>>1, wc = wave&1;
  f4 acc[4][4] = {};
  const int r0 = tid>>2, cc0 = tid&3;
  const unsigned short* Ag = A  + (size_t)(m0+r0)*CDIM + cc0*8;
  const unsigned short* Bg = Bw + (size_t)(n0+r0)*CDIM + cc0*8;

  for (int k0=0; k0<CDIM; k0+=32){
    __syncthreads();
    gll16(Ag + k0,                    As + tid*8);
    gll16(Ag + (size_t)64*CDIM + k0,  As + (256+tid)*8);
    gll16(Bg + k0,                    Bs + tid*8);
    gll16(Bg + (size_t)64*CDIM + k0,  Bs + (256+tid)*8);
    __syncthreads();
    sh8 af[4], bfr[4];
#pragma unroll
    for (int mt=0; mt<4; mt++) af[mt]  = *(const sh8*)(As + (wr*64+mt*16+c)*32 + g*8);
#pragma unroll
    for (int nt=0; nt<4; nt++) bfr[nt] = *(const sh8*)(Bs + (wc*64+nt*16+c)*32 + g*8);
#pragma unroll
    for (int mt=0; mt<4; mt++)
#pragma unroll
      for (int nt=0; nt<4; nt++)
        acc[mt][nt] = __builtin_amdgcn_mfma_f32_16x16x32_bf16(af[mt], bfr[nt], acc[mt][nt], 0,0,0);
  }

#pragma unroll
  for (int nt=0; nt<4; nt++){
    int nn = n0 + wc*64 + nt*16 + c;
    float bsv = bias[nn];
#pragma unroll
    for (int mt=0; mt<4; mt++){
      int mb = m0 + wr*64 + mt*16 + 4*g;
#pragma unroll
      for (int r=0; r<4; r++){
        float v = acc[mt][nt][r] + bsv;
        int mm = mb + r;
        if (MODE==3){
          ((unsigned short*)Cout)[(size_t)mm*CDIM + nn] = f2bf(v*C2SCALE);
        } else {
          ((float*)Cout)[(size_t)mm*CDIM + nn] = v;
        }
      }
    }
  }
}

// ---------------- fused K+V GEMM: one A-tile, two B-tiles, two outputs ----------------
__global__ __launch_bounds__(256,2) void gemm_kv(
    const unsigned short* __restrict__ A,
    const unsigned short* __restrict__ Bk, const unsigned short* __restrict__ Bv,
    const float* __restrict__ biask, const float* __restrict__ biasv,
    unsigned short* __restrict__ Kout, unsigned short* __restrict__ Vout){
  __shared__ unsigned short As[128*32];
  __shared__ unsigned short Bs1[128*32];
  __shared__ unsigned short Bs2[128*32];
  const int tid  = threadIdx.x;
  const int wave = tid>>6, lane = tid&63;
  const int g = lane>>4, c = lane&15;
  const int m0 = blockIdx.x*128, n0 = blockIdx.y*128;
  const int wr = wave>>1, wc = wave&1;
  f4 acck[4][4] = {}, accv[4][4] = {};
  const int r0 = tid>>2, cc0 = tid&3;
  const unsigned short* Ag  = A  + (size_t)(m0+r0)*CDIM + cc0*8;
  const unsigned short* Bkg = Bk + (size_t)(n0+r0)*CDIM + cc0*8;
  const unsigned short* Bvg = Bv + (size_t)(n0+r0)*CDIM + cc0*8;

  for (int k0=0; k0<CDIM; k0+=32){
    __syncthreads();
    gll16(Ag  + k0,                    As  + tid*8);
    gll16(Ag  + (size_t)64*CDIM + k0,  As  + (256+tid)*8);
    gll16(Bkg + k0,                    Bs1 + tid*8);
    gll16(Bkg + (size_t)64*CDIM + k0,  Bs1 + (256+tid)*8);
    gll16(Bvg + k0,                    Bs2 + tid*8);
    gll16(Bvg + (size_t)64*CDIM + k0,  Bs2 + (256+tid)*8);
    __syncthreads();
    sh8 af[4], bk4[4], bv4[4];
#pragma unroll
    for (int mt=0; mt<4; mt++) af[mt]  = *(const sh8*)(As  + (wr*64+mt*16+c)*32 + g*8);
#pragma unroll
    for (int nt=0; nt<4; nt++) bk4[nt] = *(const sh8*)(Bs1 + (wc*64+nt*16+c)*32 + g*8);
#pragma unroll
    for (int nt=0; nt<4; nt++) bv4[nt] = *(const sh8*)(Bs2 + (wc*64+nt*16+c)*32 + g*8);
#pragma unroll
    for (int mt=0; mt<4; mt++)
#pragma unroll
      for (int nt=0; nt<4; nt++){
        acck[mt][nt] = __builtin_amdgcn_mfma_f32_16x16x32_bf16(af[mt], bk4[nt], acck[mt][nt], 0,0,0);
        accv[mt][nt] = __builtin_amdgcn_mfma_f32_16x16x32_bf16(af[mt], bv4[nt], accv[mt][nt], 0,0,0);
      }
  }

#pragma unroll
  for (int nt=0; nt<4; nt++){
    int nn = n0 + wc*64 + nt*16 + c;
    float bkv = biask[nn], bvv = biasv[nn];
#pragma unroll
    for (int mt=0; mt<4; mt++){
      int mb = m0 + wr*64 + mt*16 + 4*g;
#pragma unroll
      for (int r=0; r<4; r++){
        int mm = mb + r;
        Kout[(size_t)mm*CDIM + nn] = f2bf(acck[mt][nt][r] + bkv);
        int t = mm>>2, bb = mm&3, h = nn>>6, d = nn&63;
        Vout[(((size_t)bb*NH + h)*HD + d)*TSEQ + t] = f2bf(accv[mt][nt][r] + bvv);
      }
    }
  }
}

// ---------------- flash attention, S^T / O^T formulation ----------------
// EXACT round-3 structure (VGPR 84, no spills, 48KB LDS, 1024 blocks) plus an
// XCD-aware block swizzle: all 16 q-blocks of a (b,h) share linear_id%8 ->
// same XCD (round-robin dispatch) -> the 512KB K/V slice stays in that XCD's
// 4MB L2 across all 16 re-reads (concurrent working set ~2-3MB < 4MB).
__global__ __launch_bounds__(256,3) void attn_kernel(
    const unsigned short* __restrict__ Q, const unsigned short* __restrict__ Kb,
    const unsigned short* __restrict__ Vt, unsigned short* __restrict__ O){
  __shared__ unsigned short Ks[128*64];        // (key, d), chunk ^= row&7
  __shared__ unsigned short Vs[64*128];        // (d, key), chunk ^= d&15
  __shared__ unsigned short Ps[4][32*64];      // per-wave (q, key-half), 8B chunk j^(c&14)
  const int tid=threadIdx.x, wave=tid>>6, lane=tid&63;
  const int g=lane>>4, c=lane&15;
  const int gx = blockIdx.x;                   // 1024 linear blocks
  const int bh = ((gx>>7)<<3) | (gx&7);        // all 16 qts of a bh share gx%8 (same XCD)
  const int qt = (gx>>3)&15;
  const int b = bh>>4, h = bh&15;
  const int qbase = qt*128 + wave*32;

  sh8 qfr[2][2];
#pragma unroll
  for (int qf=0; qf<2; qf++)
#pragma unroll
    for (int kc=0; kc<2; kc++){
      int t = qbase + qf*16 + c;
      qfr[qf][kc] = *(const sh8*)(Q + ((size_t)t*BB + b)*CDIM + h*HD + kc*32 + g*8);
    }

  f4 oacc[4][2] = {};                          // O^T frags: [d-frag][q-frag]
  float lrun[2] = {0.f, 0.f};                  // lane-local partial denominators

  for (int k0=0; k0<TSEQ; k0+=128){
    __syncthreads();
#pragma unroll
    for (int i=0; i<4; i++){                   // stage K tile (128 keys x 64 d), swizzled
      int cc = i*256+tid, row = cc>>3, ch = (cc&7) ^ (row&7);
      gll16(Kb + ((size_t)(k0+row)*BB + b)*CDIM + h*HD + ch*8, Ks + cc*8);
    }
#pragma unroll
    for (int i=0; i<4; i++){                   // stage V^T tile (64 d x 128 keys), swizzled
      int cc = i*256+tid, d = cc>>4, ch = (cc&15) ^ (d&15);
      gll16(Vt + ((size_t)(b*NH+h)*HD + d)*TSEQ + k0 + ch*8, Vs + cc*8);
    }
    __syncthreads();

    // S^T = K * Q^T : lane holds key=16kf+4g+r, q=16qf+c
    f4 sacc[8][2] = {};
#pragma unroll
    for (int kf=0; kf<8; kf++){
      sh8 af[2];
#pragma unroll
      for (int kc=0; kc<2; kc++){
        int ch = (kc*4+g) ^ (c&7);
        af[kc] = *(const sh8*)(Ks + (kf*16+c)*64 + ch*8);
      }
#pragma unroll
      for (int kc=0; kc<2; kc++)
#pragma unroll
        for (int qf=0; qf<2; qf++)
          sacc[kf][qf] = __builtin_amdgcn_mfma_f32_16x16x32_bf16(af[kc], qfr[qf][kc], sacc[kf][qf],0,0,0);
    }

    // per 64-key half: exp2 + pack to Ps, then PV MFMA (Ps is wave-private)
#pragma unroll
    for (int half=0; half<2; half++){
#pragma unroll
      for (int qf=0; qf<2; qf++){
        unsigned short* prow = Ps[wave] + (qf*16+c)*64;
#pragma unroll
        for (int kfl=0; kfl<4; kfl++){
          int kf = half*4 + kfl;
          float p0 = __builtin_amdgcn_exp2f(sacc[kf][qf][0]);
          float p1 = __builtin_amdgcn_exp2f(sacc[kf][qf][1]);
          float p2 = __builtin_amdgcn_exp2f(sacc[kf][qf][2]);
          float p3 = __builtin_amdgcn_exp2f(sacc[kf][qf][3]);
          lrun[qf] += (p0+p1)+(p2+p3);
          unsigned d0 = pk2(p1, p0);
          unsigned d1 = pk2(p3, p2);
          int js = (kfl*4+g) ^ (c&14);
          uint2 pr; pr.x = d0; pr.y = d1;
          *(uint2*)(prow + js*4) = pr;
        }
      }
#pragma unroll
      for (int kc2l=0; kc2l<2; kc2l++){
        int kc2 = half*2 + kc2l;
        sh8 pf[2];
#pragma unroll
        for (int qf=0; qf<2; qf++){
          int j0 = kc2l*8 + 2*g;
          pf[qf] = *(const sh8*)(Ps[wave] + (qf*16+c)*64 + ((j0 ^ (c&14)))*4);
        }
#pragma unroll
        for (int df=0; df<4; df++){
          int ch = (kc2*4+g) ^ c;
          sh8 vf = *(const sh8*)(Vs + (df*16+c)*128 + ch*8);
#pragma unroll
          for (int qf=0; qf<2; qf++)
            oacc[df][qf] = __builtin_amdgcn_mfma_f32_16x16x32_bf16(vf, pf[qf], oacc[df][qf],0,0,0);
        }
      }
    }
  }

  // cross-lane denominator reduction (over g groups), then normalize + store
#pragma unroll
  for (int qf=0; qf<2; qf++){
    lrun[qf] += __shfl_xor(lrun[qf], 16, 64);
    lrun[qf] += __shfl_xor(lrun[qf], 32, 64);
    float inv = 1.0f/lrun[qf];
    int t = qbase + qf*16 + c;
#pragma unroll
    for (int df=0; df<4; df++){
      uint2 pr;
      pr.x = pk2(oacc[df][qf][1]*inv, oacc[df][qf][0]*inv);
      pr.y = pk2(oacc[df][qf][3]*inv, oacc[df][qf][2]*inv);
      *(uint2*)(O + ((size_t)b*TSEQ + t)*CDIM + h*HD + df*16 + 4*g) = pr;
    }
  }
}

extern "C" void kernel_launch(void* const* d_in, const int* in_sizes, int n_in,
                              void* d_out, int out_size, void* d_ws, size_t ws_size,
                              hipStream_t stream){
  (void)in_sizes; (void)n_in; (void)out_size; (void)ws_size;
  const float* x1 = (const float*)d_in[0];
  const float* x2 = (const float*)d_in[1];
  const float* Wq = (const float*)d_in[2];
  const float* bq = (const float*)d_in[3];
  const float* Wk = (const float*)d_in[4];
  const float* bk = (const float*)d_in[5];
  const float* Wv = (const float*)d_in[6];
  const float* bv = (const float*)d_in[7];
  const float* Wu = (const float*)d_in[8];
  const float* bu = (const float*)d_in[9];

  unsigned short* ws = (unsigned short*)d_ws;
  size_t o = 0;
  unsigned short* x1b = ws + o; o += (size_t)MR*CDIM;
  unsigned short* x2b = ws + o; o += (size_t)MR*CDIM;
  unsigned short* wqb = ws + o; o += (size_t)CDIM*CDIM;
  unsigned short* wkb = ws + o; o += (size_t)CDIM*CDIM;
  unsigned short* wvb = ws + o; o += (size_t)CDIM*CDIM;
  unsigned short* wub = ws + o; o += (size_t)CDIM*CDIM;
  unsigned short* Qb  = ws + o; o += (size_t)MR*CDIM;
  unsigned short* Kbf = ws + o; o += (size_t)MR*CDIM;
  unsigned short* Vtb = ws + o; o += (size_t)MR*CDIM;
  unsigned short* Ob  = x1b;   // x1b dead after Q GEMM; reuse for attention output

  conv_x<<<dim3((MR*CDIM)/1024, 2),   256, 0, stream>>>(x1, x2, x1b, x2b);
  conv_w<<<dim3((CDIM*CDIM)/1024, 4), 256, 0, stream>>>(Wq, Wk, Wv, Wu, wqb, wkb, wvb, wub);

  dim3 gg(MR/128, CDIM/128);
  gemm_bt<3><<<gg, 256, 0, stream>>>(x1b, wqb, bq, Qb);           // Q, pre-scaled
  gemm_kv  <<<gg, 256, 0, stream>>>(x2b, wkb, wvb, bk, bv, Kbf, Vtb);
  attn_kernel<<<dim3(1024), 256, 0, stream>>>(Qb, Kbf, Vtb, Ob);
  gemm_bt<2><<<gg, 256, 0, stream>>>(Ob, wub, bu, (float*)d_out);
}

// Round 7
// 357.039 us; speedup vs baseline: 1.3079x; 1.0482x over previous
//
#include <hip/hip_runtime.h>

#define TSEQ 2048
#define BB 4
#define CDIM 1024
#define NH 16
#define HD 64
#define MR (TSEQ*BB)   // 8192 rows
#define C2SCALE 0.045084220f   // log2(e)/sqrt(CDIM) = log2(e)/32

typedef __attribute__((ext_vector_type(8))) short sh8;   // 8 bf16 = 4 VGPRs
typedef __attribute__((ext_vector_type(4))) short sh4;   // 4 bf16
typedef __attribute__((ext_vector_type(4))) float f4;    // MFMA C/D

__device__ __forceinline__ unsigned short f2bf(float x){
  unsigned u = __builtin_bit_cast(unsigned, x);
  u += 0x7fffu + ((u>>16)&1u);          // round-to-nearest-even
  return (unsigned short)(u>>16);
}

// pack two floats -> two bf16 (round-half-up) in one dword: [hi16(a) : hi16(b)]
__device__ __forceinline__ unsigned pk2(float a, float b){
  unsigned ua = __builtin_bit_cast(unsigned, a) + 0x8000u;
  unsigned ub = __builtin_bit_cast(unsigned, b) + 0x8000u;
  return __builtin_amdgcn_perm(ua, ub, 0x07060302u);  // bytes a[3],a[2],b[3],b[2]
}

__device__ __forceinline__ void gll16(const unsigned short* g, unsigned short* l){
  __builtin_amdgcn_global_load_lds(
      (const __attribute__((address_space(1))) unsigned int*)g,
      (__attribute__((address_space(3))) unsigned int*)l, 16, 0, 0);
}

// ---------------- fp32 -> bf16 conversion, fused ----------------
__global__ void conv_x(const float* __restrict__ a, const float* __restrict__ b,
                       unsigned short* __restrict__ ya, unsigned short* __restrict__ yb){
  const float* s = blockIdx.y ? b : a;
  unsigned short* d = blockIdx.y ? yb : ya;
  int i = (blockIdx.x*256 + threadIdx.x)*4;
  f4 v = *(const f4*)(s+i);
  sh4 o;
  o.x = (short)f2bf(v.x); o.y = (short)f2bf(v.y);
  o.z = (short)f2bf(v.z); o.w = (short)f2bf(v.w);
  *(sh4*)(d+i) = o;
}

__global__ void conv_w(const float* __restrict__ w0, const float* __restrict__ w1,
                       const float* __restrict__ w2, const float* __restrict__ w3,
                       unsigned short* __restrict__ y0, unsigned short* __restrict__ y1,
                       unsigned short* __restrict__ y2, unsigned short* __restrict__ y3){
  const float* s; unsigned short* d;
  switch(blockIdx.y){
    case 0: s=w0; d=y0; break;
    case 1: s=w1; d=y1; break;
    case 2: s=w2; d=y2; break;
    default: s=w3; d=y3; break;
  }
  int i = (blockIdx.x*256 + threadIdx.x)*4;
  f4 v = *(const f4*)(s+i);
  sh4 o;
  o.x = (short)f2bf(v.x); o.y = (short)f2bf(v.y);
  o.z = (short)f2bf(v.z); o.w = (short)f2bf(v.w);
  *(sh4*)(d+i) = o;
}

// ---------------- final GEMM: C[m][n] = sum_k A[m][k]*W[n][k] + bias[n], fp32 out ----
__global__ __launch_bounds__(256,2) void gemm_u(
    const unsigned short* __restrict__ A, const unsigned short* __restrict__ Bw,
    const float* __restrict__ bias, float* __restrict__ Cout){
  __shared__ unsigned short As[128*32];
  __shared__ unsigned short Bs[128*32];
  const int tid  = threadIdx.x;
  const int wave = tid>>6, lane = tid&63;
  const int g = lane>>4, c = lane&15;
  const int m0 = blockIdx.x*128, n0 = blockIdx.y*128;
  const int wr = wave>>1, wc = wave&1;
  f4 acc[4][4] = {};
  const int r0 = tid>>2, cc0 = tid&3;
  const unsigned short* Ag = A  + (size_t)(m0+r0)*CDIM + cc0*8;
  const unsigned short* Bg = Bw + (size_t)(n0+r0)*CDIM + cc0*8;

  for (int k0=0; k0<CDIM; k0+=32){
    __syncthreads();
    gll16(Ag + k0,                    As + tid*8);
    gll16(Ag + (size_t)64*CDIM + k0,  As + (256+tid)*8);
    gll16(Bg + k0,                    Bs + tid*8);
    gll16(Bg + (size_t)64*CDIM + k0,  Bs + (256+tid)*8);
    __syncthreads();
    sh8 af[4], bfr[4];
#pragma unroll
    for (int mt=0; mt<4; mt++) af[mt]  = *(const sh8*)(As + (wr*64+mt*16+c)*32 + g*8);
#pragma unroll
    for (int nt=0; nt<4; nt++) bfr[nt] = *(const sh8*)(Bs + (wc*64+nt*16+c)*32 + g*8);
#pragma unroll
    for (int mt=0; mt<4; mt++)
#pragma unroll
      for (int nt=0; nt<4; nt++)
        acc[mt][nt] = __builtin_amdgcn_mfma_f32_16x16x32_bf16(af[mt], bfr[nt], acc[mt][nt], 0,0,0);
  }

#pragma unroll
  for (int nt=0; nt<4; nt++){
    int nn = n0 + wc*64 + nt*16 + c;
    float bsv = bias[nn];
#pragma unroll
    for (int mt=0; mt<4; mt++){
      int mb = m0 + wr*64 + mt*16 + 4*g;
#pragma unroll
      for (int r=0; r<4; r++)
        Cout[(size_t)(mb+r)*CDIM + nn] = acc[mt][nt][r] + bsv;
    }
  }
}

// ---------------- fused Q/K/V projection: blockIdx.z selects output ----------------
// z=0: Q = x1@Wq^T+bq, scaled by C2SCALE, bf16 row-major
// z=1: K = x2@Wk^T+bk, bf16 row-major
// z=2: V = x2@Wv^T+bv, bf16 transposed to (b,h,d,t)
// 1536 blocks (6/CU) vs two grid-starved launches at 2/CU.
__global__ __launch_bounds__(256,2) void gemm_qkv(
    const unsigned short* __restrict__ x1b, const unsigned short* __restrict__ x2b,
    const unsigned short* __restrict__ wq, const unsigned short* __restrict__ wk,
    const unsigned short* __restrict__ wv,
    const float* __restrict__ bq, const float* __restrict__ bk, const float* __restrict__ bv,
    unsigned short* __restrict__ Qo, unsigned short* __restrict__ Ko,
    unsigned short* __restrict__ Vo){
  __shared__ unsigned short As[128*32];
  __shared__ unsigned short Bs[128*32];
  const int z = blockIdx.z;
  const unsigned short* A  = (z==0) ? x1b : x2b;
  const unsigned short* Bw = (z==0) ? wq : (z==1) ? wk : wv;
  const float* bias        = (z==0) ? bq : (z==1) ? bk : bv;
  const int tid  = threadIdx.x;
  const int wave = tid>>6, lane = tid&63;
  const int g = lane>>4, c = lane&15;
  const int m0 = blockIdx.x*128, n0 = blockIdx.y*128;
  const int wr = wave>>1, wc = wave&1;
  f4 acc[4][4] = {};
  const int r0 = tid>>2, cc0 = tid&3;
  const unsigned short* Ag = A  + (size_t)(m0+r0)*CDIM + cc0*8;
  const unsigned short* Bg = Bw + (size_t)(n0+r0)*CDIM + cc0*8;

  for (int k0=0; k0<CDIM; k0+=32){
    __syncthreads();
    gll16(Ag + k0,                    As + tid*8);
    gll16(Ag + (size_t)64*CDIM + k0,  As + (256+tid)*8);
    gll16(Bg + k0,                    Bs + tid*8);
    gll16(Bg + (size_t)64*CDIM + k0,  Bs + (256+tid)*8);
    __syncthreads();
    sh8 af[4], bfr[4];
#pragma unroll
    for (int mt=0; mt<4; mt++) af[mt]  = *(const sh8*)(As + (wr*64+mt*16+c)*32 + g*8);
#pragma unroll
    for (int nt=0; nt<4; nt++) bfr[nt] = *(const sh8*)(Bs + (wc*64+nt*16+c)*32 + g*8);
#pragma unroll
    for (int mt=0; mt<4; mt++)
#pragma unroll
      for (int nt=0; nt<4; nt++)
        acc[mt][nt] = __builtin_amdgcn_mfma_f32_16x16x32_bf16(af[mt], bfr[nt], acc[mt][nt], 0,0,0);
  }

#pragma unroll
  for (int nt=0; nt<4; nt++){
    int nn = n0 + wc*64 + nt*16 + c;
    float bsv = bias[nn];
#pragma unroll
    for (int mt=0; mt<4; mt++){
      int mb = m0 + wr*64 + mt*16 + 4*g;
#pragma unroll
      for (int r=0; r<4; r++){
        float v = acc[mt][nt][r] + bsv;
        int mm = mb + r;
        if (z==0){
          Qo[(size_t)mm*CDIM + nn] = f2bf(v*C2SCALE);
        } else if (z==1){
          Ko[(size_t)mm*CDIM + nn] = f2bf(v);
        } else {
          int t = mm>>2, bb = mm&3, h = nn>>6, d = nn&63;
          Vo[(((size_t)bb*NH + h)*HD + d)*TSEQ + t] = f2bf(v);
        }
      }
    }
  }
}

// ---------------- flash attention, S^T / O^T, register-pipelined staging --------
// Round-7 change: K/V staging is global_load -> VGPR (issued BEFORE compute) ->
// ds_write (AFTER compute). Loads are in flight during ~2300cy of compute, so
// the vmcnt wait before ds_write / barrier drains are free — removes the
// stage-barrier serialization that left all pipes <45% busy in round 6.
// Single 48KB LDS buffer (3 blocks/CU). XCD swizzle retained (FETCH 36MB, L2-hit).
__global__ __launch_bounds__(256,3) void attn_kernel(
    const unsigned short* __restrict__ Q, const unsigned short* __restrict__ Kb,
    const unsigned short* __restrict__ Vt, unsigned short* __restrict__ O){
  __shared__ unsigned short Ks[128*64];        // (key, d), chunk ^= row&7
  __shared__ unsigned short Vs[64*128];        // (d, key), chunk ^= d&15
  __shared__ unsigned short Ps[4][32*64];      // per-wave (q, key-half), 8B chunk j^(c&14)
  const int tid=threadIdx.x, wave=tid>>6, lane=tid&63;
  const int g=lane>>4, c=lane&15;
  const int gx = blockIdx.x;                   // 1024 linear blocks
  const int bh = ((gx>>7)<<3) | (gx&7);        // all 16 qts of a bh share gx%8 (same XCD)
  const int qt = (gx>>3)&15;
  const int b = bh>>4, h = bh&15;
  const int qbase = qt*128 + wave*32;

  // staging address bases (k0-invariant parts)
  const unsigned short* kbase[4];
  const unsigned short* vbase[4];
#pragma unroll
  for (int i=0; i<4; i++){
    int cc = i*256+tid;
    int krow = cc>>3, kch = (cc&7) ^ (krow&7);
    kbase[i] = Kb + ((size_t)krow*BB + b)*CDIM + h*HD + kch*8;
    int vd = cc>>4, vch = (cc&15) ^ (vd&15);
    vbase[i] = Vt + ((size_t)(b*NH+h)*HD + vd)*TSEQ + vch*8;
  }

  sh8 qfr[2][2];
#pragma unroll
  for (int qf=0; qf<2; qf++)
#pragma unroll
    for (int kc=0; kc<2; kc++){
      int t = qbase + qf*16 + c;
      qfr[qf][kc] = *(const sh8*)(Q + ((size_t)t*BB + b)*CDIM + h*HD + kc*32 + g*8);
    }

  f4 oacc[4][2] = {};                          // O^T frags: [d-frag][q-frag]
  float lrun[2] = {0.f, 0.f};                  // lane-local partial denominators

  // prologue: load tile 0 -> regs -> LDS
  f4 kreg[4], vreg[4];
#pragma unroll
  for (int i=0; i<4; i++){
    kreg[i] = *(const f4*)(kbase[i]);
    vreg[i] = *(const f4*)(vbase[i]);
  }
#pragma unroll
  for (int i=0; i<4; i++){
    *(f4*)(Ks + (i*256+tid)*8) = kreg[i];
    *(f4*)(Vs + (i*256+tid)*8) = vreg[i];
  }
  __syncthreads();

  for (int iter=0; iter<TSEQ/128; iter++){
    // issue next tile's global loads (in flight during compute below)
    if (iter < TSEQ/128-1){
      int k0n = (iter+1)*128;
#pragma unroll
      for (int i=0; i<4; i++){
        kreg[i] = *(const f4*)(kbase[i] + (size_t)k0n*BB*CDIM);
        vreg[i] = *(const f4*)(vbase[i] + k0n);
      }
    }

    // ---- compute on current LDS tile ----
    // S^T = K * Q^T : lane holds key=16kf+4g+r, q=16qf+c
    f4 sacc[8][2] = {};
#pragma unroll
    for (int kf=0; kf<8; kf++){
      sh8 af[2];
#pragma unroll
      for (int kc=0; kc<2; kc++){
        int ch = (kc*4+g) ^ (c&7);
        af[kc] = *(const sh8*)(Ks + (kf*16+c)*64 + ch*8);
      }
#pragma unroll
      for (int kc=0; kc<2; kc++)
#pragma unroll
        for (int qf=0; qf<2; qf++)
          sacc[kf][qf] = __builtin_amdgcn_mfma_f32_16x16x32_bf16(af[kc], qfr[qf][kc], sacc[kf][qf],0,0,0);
    }

    // per 64-key half: exp2 + pack to Ps, then PV MFMA (Ps is wave-private)
#pragma unroll
    for (int half=0; half<2; half++){
#pragma unroll
      for (int qf=0; qf<2; qf++){
        unsigned short* prow = Ps[wave] + (qf*16+c)*64;
#pragma unroll
        for (int kfl=0; kfl<4; kfl++){
          int kf = half*4 + kfl;
          float p0 = __builtin_amdgcn_exp2f(sacc[kf][qf][0]);
          float p1 = __builtin_amdgcn_exp2f(sacc[kf][qf][1]);
          float p2 = __builtin_amdgcn_exp2f(sacc[kf][qf][2]);
          float p3 = __builtin_amdgcn_exp2f(sacc[kf][qf][3]);
          lrun[qf] += (p0+p1)+(p2+p3);
          uint2 pr; pr.x = pk2(p1, p0); pr.y = pk2(p3, p2);
          int js = (kfl*4+g) ^ (c&14);
          *(uint2*)(prow + js*4) = pr;
        }
      }
#pragma unroll
      for (int kc2l=0; kc2l<2; kc2l++){
        int kc2 = half*2 + kc2l;
        sh8 pf[2];
#pragma unroll
        for (int qf=0; qf<2; qf++){
          int j0 = kc2l*8 + 2*g;
          pf[qf] = *(const sh8*)(Ps[wave] + (qf*16+c)*64 + ((j0 ^ (c&14)))*4);
        }
#pragma unroll
        for (int df=0; df<4; df++){
          int ch = (kc2*4+g) ^ c;
          sh8 vf = *(const sh8*)(Vs + (df*16+c)*128 + ch*8);
#pragma unroll
          for (int qf=0; qf<2; qf++)
            oacc[df][qf] = __builtin_amdgcn_mfma_f32_16x16x32_bf16(vf, pf[qf], oacc[df][qf],0,0,0);
        }
      }
    }

    // ---- rotate: all waves done reading, then overwrite LDS with next tile ----
    __syncthreads();
    if (iter < TSEQ/128-1){
#pragma unroll
      for (int i=0; i<4; i++){
        *(f4*)(Ks + (i*256+tid)*8) = kreg[i];
        *(f4*)(Vs + (i*256+tid)*8) = vreg[i];
      }
      __syncthreads();
    }
  }

  // cross-lane denominator reduction (over g groups), then normalize + store
#pragma unroll
  for (int qf=0; qf<2; qf++){
    lrun[qf] += __shfl_xor(lrun[qf], 16, 64);
    lrun[qf] += __shfl_xor(lrun[qf], 32, 64);
    float inv = 1.0f/lrun[qf];
    int t = qbase + qf*16 + c;
#pragma unroll
    for (int df=0; df<4; df++){
      uint2 pr;
      pr.x = pk2(oacc[df][qf][1]*inv, oacc[df][qf][0]*inv);
      pr.y = pk2(oacc[df][qf][3]*inv, oacc[df][qf][2]*inv);
      *(uint2*)(O + ((size_t)b*TSEQ + t)*CDIM + h*HD + df*16 + 4*g) = pr;
    }
  }
}

extern "C" void kernel_launch(void* const* d_in, const int* in_sizes, int n_in,
                              void* d_out, int out_size, void* d_ws, size_t ws_size,
                              hipStream_t stream){
  (void)in_sizes; (void)n_in; (void)out_size; (void)ws_size;
  const float* x1 = (const float*)d_in[0];
  const float* x2 = (const float*)d_in[1];
  const float* Wq = (const float*)d_in[2];
  const float* bq = (const float*)d_in[3];
  const float* Wk = (const float*)d_in[4];
  const float* bk = (const float*)d_in[5];
  const float* Wv = (const float*)d_in[6];
  const float* bv = (const float*)d_in[7];
  const float* Wu = (const float*)d_in[8];
  const float* bu = (const float*)d_in[9];

  unsigned short* ws = (unsigned short*)d_ws;
  size_t o = 0;
  unsigned short* x1b = ws + o; o += (size_t)MR*CDIM;
  unsigned short* x2b = ws + o; o += (size_t)MR*CDIM;
  unsigned short* wqb = ws + o; o += (size_t)CDIM*CDIM;
  unsigned short* wkb = ws + o; o += (size_t)CDIM*CDIM;
  unsigned short* wvb = ws + o; o += (size_t)CDIM*CDIM;
  unsigned short* wub = ws + o; o += (size_t)CDIM*CDIM;
  unsigned short* Qb  = ws + o; o += (size_t)MR*CDIM;
  unsigned short* Kbf = ws + o; o += (size_t)MR*CDIM;
  unsigned short* Vtb = ws + o; o += (size_t)MR*CDIM;
  unsigned short* Ob  = x1b;   // x1b dead after QKV GEMM; reuse for attention output

  conv_x<<<dim3((MR*CDIM)/1024, 2),   256, 0, stream>>>(x1, x2, x1b, x2b);
  conv_w<<<dim3((CDIM*CDIM)/1024, 4), 256, 0, stream>>>(Wq, Wk, Wv, Wu, wqb, wkb, wvb, wub);

  gemm_qkv<<<dim3(MR/128, CDIM/128, 3), 256, 0, stream>>>(
      x1b, x2b, wqb, wkb, wvb, bq, bk, bv, Qb, Kbf, Vtb);
  attn_kernel<<<dim3(1024), 256, 0, stream>>>(Qb, Kbf, Vtb, Ob);
  gemm_u<<<dim3(MR/128, CDIM/128), 256, 0, stream>>>(Ob, wub, bu, (float*)d_out);
}